// Round 1
// baseline (2295.116 us; speedup 1.0000x reference)
//
#include <hip/hip_runtime.h>

#define BB 65536
#define LL 128
#define HH 20
#define HH2 2

__device__ __forceinline__ float fexp(float x) {
    return __builtin_amdgcn_exp2f(x * 1.4426950408889634f);   // e^x via 2^(x*log2e)
}
__device__ __forceinline__ float frcp(float x) { return __builtin_amdgcn_rcpf(x); }
__device__ __forceinline__ float sigf(float x) { return frcp(1.0f + fexp(-x)); }
__device__ __forceinline__ float tanh_(float x) { return 1.0f - 2.0f * frcp(fexp(2.0f * x) + 1.0f); }
__device__ __forceinline__ float lrelu(float x) { return fmaxf(x, 0.01f * x); }
__device__ __forceinline__ void fma4(float4& a, float s, const float4 w) {
    a.x = fmaf(s, w.x, a.x);
    a.y = fmaf(s, w.y, a.y);
    a.z = fmaf(s, w.z, a.z);
    a.w = fmaf(s, w.w, a.w);
}

// One thread per batch element. Weights packed gate-major into LDS float4s:
// sW1[j][k].{x,y,z,w} = W[gate*20+j][k'] for gate = i,f,g,o
//   k = 0,1   : Wih1 columns (input x0,x1)
//   k = 2..21 : Whh1 columns (h1[0..19])
//   k = 22    : bih1+bhh1
// sW2[j][k] analogous: k=0..39 out1, k=40,41 h2, k=42 bias.
__global__ __launch_bounds__(256, 1) void sampler_lstm(
    const float* __restrict__ mu, const float* __restrict__ log_var,
    const float* __restrict__ eps0, const float* __restrict__ eps,
    const float* __restrict__ Wih1, const float* __restrict__ Whh1,
    const float* __restrict__ bih1, const float* __restrict__ bhh1,
    const float* __restrict__ Wih2, const float* __restrict__ Whh2,
    const float* __restrict__ bih2, const float* __restrict__ bhh2,
    float* __restrict__ out)
{
    __shared__ float4 sW1[HH][23];
    __shared__ float4 sW2[HH2][43];

    const int tid = threadIdx.x;
    for (int idx = tid; idx < HH * 23; idx += 256) {
        int j = idx / 23, k = idx % 23;
        float4 v;
        float* vp = (float*)&v;
        #pragma unroll
        for (int g = 0; g < 4; ++g) {
            int row = g * HH + j;
            float val;
            if (k < 2)       val = Wih1[row * 2 + k];
            else if (k < 22) val = Whh1[row * HH + (k - 2)];
            else             val = bih1[row] + bhh1[row];
            vp[g] = val;
        }
        sW1[j][k] = v;
    }
    for (int idx = tid; idx < HH2 * 43; idx += 256) {
        int j = idx / 43, k = idx % 43;
        float4 v;
        float* vp = (float*)&v;
        #pragma unroll
        for (int g = 0; g < 4; ++g) {
            int row = g * HH2 + j;
            float val;
            if (k < 40)      val = Wih2[row * 40 + k];
            else if (k < 42) val = Whh2[row * 2 + (k - 40)];
            else             val = bih2[row] + bhh2[row];
            vp[g] = val;
        }
        sW2[j][k] = v;
    }
    __syncthreads();

    const int b = blockIdx.x * 256 + tid;
    const float* murow = mu + (size_t)b * LL;
    float* out_mu = out + (size_t)b * LL;
    float* out_lv = out_mu + (size_t)BB * LL;
    float* out_sp = out_mu + 2ul * (size_t)BB * LL;

    float h1[HH], c1[HH];
    #pragma unroll
    for (int j = 0; j < HH; ++j) { h1[j] = 0.f; c1[j] = 0.f; }
    float h2a = 0.f, h2b = 0.f, c2a = 0.f, c2b = 0.f;

    float x0 = eps0[b] * fexp(0.5f * log_var[(size_t)b * LL]) + murow[0];
    float x1 = 0.f;

    #pragma unroll 1
    for (int t = 0; t < LL; ++t) {
        float mu_t  = murow[t];                       // strided, L1-cached (64B line reused 16 steps)
        float eps_t = eps[(size_t)t * BB + b];        // coalesced

        // ---- layer 1 LSTM cell ----
        float h1n[HH];
        #pragma unroll
        for (int j = 0; j < HH; ++j) {
            float4 a = sW1[j][22];                    // bias (i,f,g,o)
            fma4(a, x0, sW1[j][0]);
            fma4(a, x1, sW1[j][1]);
            #pragma unroll
            for (int k = 0; k < HH; ++k) fma4(a, h1[k], sW1[j][2 + k]);
            float cn = sigf(a.y) * c1[j] + sigf(a.x) * tanh_(a.z);
            c1[j] = cn;
            h1n[j] = sigf(a.w) * tanh_(cn);
        }

        // out1 = leaky_relu(concat(h1_new, c1_new))
        float o1h[HH], o1c[HH];
        #pragma unroll
        for (int k = 0; k < HH; ++k) { o1h[k] = lrelu(h1n[k]); o1c[k] = lrelu(c1[k]); }

        // ---- layer 2 LSTM cell ----
        float4 a0 = sW2[0][42];
        float4 a1 = sW2[1][42];
        #pragma unroll
        for (int k = 0; k < HH; ++k) { fma4(a0, o1h[k], sW2[0][k]);      fma4(a1, o1h[k], sW2[1][k]); }
        #pragma unroll
        for (int k = 0; k < HH; ++k) { fma4(a0, o1c[k], sW2[0][20 + k]); fma4(a1, o1c[k], sW2[1][20 + k]); }
        fma4(a0, h2a, sW2[0][40]); fma4(a1, h2a, sW2[1][40]);
        fma4(a0, h2b, sW2[0][41]); fma4(a1, h2b, sW2[1][41]);
        float cn0 = sigf(a0.y) * c2a + sigf(a0.x) * tanh_(a0.z);
        float cn1 = sigf(a1.y) * c2b + sigf(a1.x) * tanh_(a1.z);
        c2a = cn0; c2b = cn1;
        h2a = sigf(a0.w) * tanh_(cn0);
        h2b = sigf(a1.w) * tanh_(cn1);

        float samp = eps_t * fexp(0.5f * h2b) + h2a;
        out_mu[t] = h2a;
        out_lv[t] = h2b;
        out_sp[t] = samp;

        #pragma unroll
        for (int j = 0; j < HH; ++j) h1[j] = h1n[j];
        x0 = mu_t;
        x1 = (float)t;
    }
}

extern "C" void kernel_launch(void* const* d_in, const int* in_sizes, int n_in,
                              void* d_out, int out_size, void* d_ws, size_t ws_size,
                              hipStream_t stream) {
    sampler_lstm<<<dim3(BB / 256), dim3(256), 0, stream>>>(
        (const float*)d_in[0],  (const float*)d_in[1],  (const float*)d_in[2],
        (const float*)d_in[3],  (const float*)d_in[4],  (const float*)d_in[5],
        (const float*)d_in[6],  (const float*)d_in[7],  (const float*)d_in[8],
        (const float*)d_in[9],  (const float*)d_in[10], (const float*)d_in[11],
        (float*)d_out);
}